// Round 6
// baseline (103.153 us; speedup 1.0000x reference)
//
#include <hip/hip_runtime.h>
#include <math.h>

// Problem constants
#define NQ 10
#define DIM 1024          // 2^10
#define NPTS 64
#define DFEAT 10
#define NLAYERS 5
#define SREGS 4           // amps per thread in state kernel (DIM / 256)
#define NBUCKET 16        // atomic-accumulator buckets for gram reduce

#define IS2 0.70710678118654752440f

// ws layout: psi (64*1024 float2 = 512 KB) | slkb[16] | skkb[16] | ticket
#define ACC_OFF ((size_t)NPTS * DIM * sizeof(float2))

// ---------------------------------------------------------------------------
// Kernel 1: psi_i = U(x_i)|0> per data point. 256 threads (4 waves)/block.
// Amplitude index idx = (r<<8)|(wv<<6)|lane:
//   bits 0..5 -> lane (shfl_xor), bits 6..7 -> wave (LDS exchange),
//   bits 8..9 -> register r (in-register butterfly).
//
// R4 lesson: fully-unrolled 1-wave version was INSTRUCTION-FETCH bound
// (FETCH_SIZE ~= 8 XCDs x code size, VALUBusy <1%). Keep loops ROLLED so the
// layer body is fetched once, gate coeffs in a small LDS table.
// R5 additions (verified algebra from R3/R4, absmax==0):
//  - layer 0's 1q gates act on |0> -> product state, zero shuffles/barriers
//  - layer 5: ring diag + RY are data-independent outer unitaries -> cancel
//    in |<psi_j|psi_i>|^2 (c=1,s=0 in M; ring skipped)
//
// Fused 1q gate per (layer,qubit): M = RY(t)*RZ(x)*H, cx=cos(x/2),
// sx=sin(x/2), c=cos(t/2), s=sin(t/2), p=(c+s)/sqrt2, q=(c-s)/sqrt2:
//   m00=( q*cx, -p*sx)  m01=( p*cx, -q*sx)
//   m10=( p*cx,  q*sx)  m11=(-q*cx, -p*sx)     (store m00,m01 as float4)
// x angle is x[9-q] in every layer (all starts % 10 == 0).
// Block 0 also zeroes the gram accumulators (ws is re-poisoned each call).
// ---------------------------------------------------------------------------
__global__ __launch_bounds__(256) void state_kernel(
    const float* __restrict__ data,     // (64,10)
    const float* __restrict__ params,   // (5,2,10)
    float2* __restrict__ psi,           // (64,1024)
    float* __restrict__ acc)            // slkb[16] skkb[16] ticket
{
    const int i    = blockIdx.x;
    const int tid  = threadIdx.x;
    const int lane = tid & 63;
    const int wv   = tid >> 6;

    // zero gram accumulators + ticket (visible to gram via kernel boundary)
    if (i == 0 && tid < 2 * NBUCKET + 1) acc[tid] = 0.f;

    __shared__ float4 mc[NLAYERS][NQ];   // (m00r, m00i, m01r, m01i)
    __shared__ float2 xbuf[16][64];      // [wv*4+r][lane] exchange buffer

    // ---- precompute fused gate coefficients (50 threads, once) ----
    if (tid < NLAYERS * NQ) {
        const int L = tid / NQ, q = tid - L * NQ;
        const float xh = 0.5f * data[i * DFEAT + (9 - q)];
        const float cx = __cosf(xh), sx = __sinf(xh);
        float c = 1.f, s = 0.f;
        if (L != NLAYERS - 1) {
            const float th = 0.5f * params[L * 2 * NQ + q];
            c = __cosf(th); s = __sinf(th);
        }
        const float p = (c + s) * IS2, qm = (c - s) * IS2;
        mc[L][q] = make_float4(qm * cx, -p * sx, p * cx, -qm * sx);
    }
    __syncthreads();

    float re[SREGS], im[SREGS];

    // ---- layer 0: product state (no shuffles, no barriers) ----
    // u0 = m00 = (mc.x, mc.y); u1 = m10 = (mc.z, -mc.w)
    {
        float Pr = 1.f, Pi = 0.f;       // product over qubits 0..7
#pragma unroll 1
        for (int q = 0; q < 8; ++q) {
            const float4 m = mc[0][q];
            const int b = (q < 6) ? ((lane >> q) & 1) : ((wv >> (q - 6)) & 1);
            const float fr = b ? m.z : m.x;
            const float fi = b ? -m.w : m.y;
            const float nr = Pr * fr - Pi * fi;
            const float ni = Pr * fi + Pi * fr;
            Pr = nr; Pi = ni;
        }
        const float4 m8 = mc[0][8], m9 = mc[0][9];
        const float u8r[2] = {m8.x, m8.z},  u8i[2] = {m8.y, -m8.w};
        const float u9r[2] = {m9.x, m9.z},  u9i[2] = {m9.y, -m9.w};
#pragma unroll
        for (int r = 0; r < SREGS; ++r) {
            const int b8 = r & 1, b9 = (r >> 1) & 1;
            const float vr = u8r[b8] * u9r[b9] - u8i[b8] * u9i[b9];
            const float vi = u8r[b8] * u9i[b9] + u8i[b8] * u9r[b9];
            re[r] = Pr * vr - Pi * vi;
            im[r] = Pr * vi + Pi * vr;
        }
    }

#pragma unroll 1
    for (int L = 0; L < NLAYERS; ++L) {
        if (L > 0) {
            // ---- qubits 0..5: cross-lane butterfly (rolled) ----
#pragma unroll 1
            for (int q = 0; q < 6; ++q) {
                const float4 m = mc[L][q];
                const int   b = (lane >> q) & 1;
                const float msr = b ? -m.x : m.x;   // m11r / m00r
                const float msi = m.y;              // m11i == m00i
                const float mpr = m.z;              // m10r == m01r
                const float mpi = b ? -m.w : m.w;   // m10i / m01i
                float pr[SREGS], pi[SREGS];
#pragma unroll
                for (int r = 0; r < SREGS; ++r) {
                    pr[r] = __shfl_xor(re[r], 1 << q, 64);
                    pi[r] = __shfl_xor(im[r], 1 << q, 64);
                }
#pragma unroll
                for (int r = 0; r < SREGS; ++r) {
                    const float nr = msr * re[r] - msi * im[r] + mpr * pr[r] - mpi * pi[r];
                    const float ni = msr * im[r] + msi * re[r] + mpr * pi[r] + mpi * pr[r];
                    re[r] = nr; im[r] = ni;
                }
            }

            // ---- qubits 6..7: cross-wave via LDS (rolled) ----
#pragma unroll 1
            for (int q = 6; q < 8; ++q) {
                const float4 m = mc[L][q];
                const int   b = (wv >> (q - 6)) & 1;
                const float msr = b ? -m.x : m.x;
                const float msi = m.y;
                const float mpr = m.z;
                const float mpi = b ? -m.w : m.w;
#pragma unroll
                for (int r = 0; r < SREGS; ++r)
                    xbuf[(wv << 2) | r][lane] = make_float2(re[r], im[r]);
                __syncthreads();
                const int pw = wv ^ (1 << (q - 6));
#pragma unroll
                for (int r = 0; r < SREGS; ++r) {
                    const float2 p2 = xbuf[(pw << 2) | r][lane];
                    const float nr = msr * re[r] - msi * im[r] + mpr * p2.x - mpi * p2.y;
                    const float ni = msr * im[r] + msi * re[r] + mpr * p2.y + mpi * p2.x;
                    re[r] = nr; im[r] = ni;
                }
                __syncthreads();
            }

            // ---- qubits 8..9: in-register butterfly ----
#pragma unroll
            for (int q = 8; q < 10; ++q) {
                const int mask = 1 << (q - 8);
                const float4 m = mc[L][q];
                const float m00r = m.x, m00i = m.y, m01r = m.z, m01i = m.w;
                const float m10r = m.z, m10i = -m.w, m11r = -m.x, m11i = m.y;
#pragma unroll
                for (int r = 0; r < SREGS; ++r) {
                    if (!(r & mask)) {
                        const int r1 = r | mask;
                        const float a0r = re[r],  a0i = im[r];
                        const float a1r = re[r1], a1i = im[r1];
                        re[r]  = m00r * a0r - m00i * a0i + m01r * a1r - m01i * a1i;
                        im[r]  = m00r * a0i + m00i * a0r + m01r * a1i + m01i * a1r;
                        re[r1] = m10r * a0r - m10i * a0i + m11r * a1r - m11i * a1i;
                        im[r1] = m10r * a0i + m10i * a0r + m11r * a1i + m11i * a1r;
                    }
                }
            }
        }

        // ---- crz ring diagonal (skip layer 5: cancels in |<.|.>|^2) ----
        if (L < NLAYERS - 1) {
            const float* rg = params + L * 2 * NQ + NQ;
            float ph[SREGS] = {0.f, 0.f, 0.f, 0.f};
#pragma unroll 1
            for (int n = 0; n < NQ; ++n) {
                const int   nn = (n == 9) ? 0 : (n + 1);
                const float g  = rg[n];     // wave-uniform -> s_load
#pragma unroll
                for (int r = 0; r < SREGS; ++r) {
                    const int idx = (r << 8) | (wv << 6) | lane;
                    const float t = (((idx >> nn) & 1) ? 0.5f : -0.5f) * g;
                    ph[r] += ((idx >> n) & 1) ? t : 0.f;
                }
            }
#pragma unroll
            for (int r = 0; r < SREGS; ++r) {
                const float s = __sinf(ph[r]), c = __cosf(ph[r]);
                const float nr = re[r] * c - im[r] * s;
                const float ni = re[r] * s + im[r] * c;
                re[r] = nr; im[r] = ni;
            }
        }
    }

    // write psi_i (coalesced float2)
    float2* out = psi + i * DIM;
#pragma unroll
    for (int r = 0; r < SREGS; ++r)
        out[(r << 8) | (wv << 6) | lane] = make_float2(re[r], im[r]);
}

// ---------------------------------------------------------------------------
// Kernel 2: fused gram + KTA reduce.
// Pair p = blockIdx*4 + wave; i=p>>6, j=p&63. Only j>=i computed (weight 2
// off-diagonal). Block-level partial sums -> bucketed device atomics
// (NBUCKET=16 -> 64 adds/address, negligible contention). Last block by
// ticket sums buckets (atomicAdd(p,0) = device-scope read) and writes
// out = slk / sqrt(skk * sll), sll = (sum l_i^2)^2.
// ---------------------------------------------------------------------------
__global__ __launch_bounds__(256) void gram_kernel(
    const float4* __restrict__ psi4,  // (64, 512) float4 view of psi
    const float* __restrict__ labels, // (64,)
    float* __restrict__ acc,          // slkb[16] skkb[16] ticket
    float* __restrict__ out)          // (1,)
{
    __shared__ float sm[2][4];
    const int wave = threadIdx.x >> 6;
    const int lane = threadIdx.x & 63;
    const int p    = blockIdx.x * 4 + wave;   // 0..4095
    const int i    = p >> 6;
    const int j    = p & 63;

    float slk_w = 0.f, skk_w = 0.f;
    if (j >= i) {
        const float4* a = psi4 + i * (DIM / 2);
        const float4* b = psi4 + j * (DIM / 2);
        float zr = 0.f, zi = 0.f;   // <psi_j|psi_i> = sum conj(b)*a
#pragma unroll
        for (int r = 0; r < 8; ++r) {
            const int k = (r << 6) | lane;
            float4 av = a[k], bv = b[k];
            zr += bv.x * av.x + bv.y * av.y + bv.z * av.z + bv.w * av.w;
            zi += bv.x * av.y - bv.y * av.x + bv.z * av.w - bv.w * av.z;
        }
#pragma unroll
        for (int off = 32; off; off >>= 1) {
            zr += __shfl_xor(zr, off, 64);
            zi += __shfl_xor(zi, off, 64);
        }
        const float k = zr * zr + zi * zi;
        const float w = (i == j) ? 1.f : 2.f;
        slk_w = w * labels[i] * labels[j] * k;
        skk_w = w * k * k;
    }
    if (lane == 0) { sm[0][wave] = slk_w; sm[1][wave] = skk_w; }
    __syncthreads();

    if (threadIdx.x == 0) {
        const float bs = sm[0][0] + sm[0][1] + sm[0][2] + sm[0][3];
        const float bk = sm[1][0] + sm[1][1] + sm[1][2] + sm[1][3];
        const int bkt = blockIdx.x & (NBUCKET - 1);
        atomicAdd(&acc[bkt], bs);
        atomicAdd(&acc[NBUCKET + bkt], bk);
        __threadfence();
        unsigned* ticket = (unsigned*)(acc + 2 * NBUCKET);
        const unsigned t = atomicAdd(ticket, 1u);
        if (t == (unsigned)(gridDim.x - 1)) {
            // last block: device-scope reads via atomicAdd(p, 0)
            float slk = 0.f, skk = 0.f;
#pragma unroll
            for (int q = 0; q < NBUCKET; ++q) {
                slk += atomicAdd(&acc[q], 0.f);
                skk += atomicAdd(&acc[NBUCKET + q], 0.f);
            }
            float sl2 = 0.f;
            for (int q = 0; q < NPTS; ++q) { const float l = labels[q]; sl2 += l * l; }
            out[0] = slk / sqrtf(skk * (sl2 * sl2));
        }
    }
}

extern "C" void kernel_launch(void* const* d_in, const int* in_sizes, int n_in,
                              void* d_out, int out_size, void* d_ws, size_t ws_size,
                              hipStream_t stream) {
    const float* data   = (const float*)d_in[0];  // (64,10)
    const float* labels = (const float*)d_in[1];  // (64,)
    const float* params = (const float*)d_in[2];  // (5,2,10)
    float* out = (float*)d_out;

    float2* psi = (float2*)d_ws;
    float*  acc = (float*)((char*)d_ws + ACC_OFF);

    state_kernel<<<NPTS,            256, 0, stream>>>(data, params, psi, acc);
    gram_kernel <<<NPTS * NPTS / 4, 256, 0, stream>>>((const float4*)psi, labels, acc, out);
}

// Round 7
// 73.894 us; speedup vs baseline: 1.3960x; 1.3960x over previous
//
#include <hip/hip_runtime.h>
#include <math.h>

// Problem constants
#define NQ 10
#define DIM 1024          // 2^10
#define NPTS 64
#define DFEAT 10
#define NLAYERS 5
#define NPAIR 2080        // 64*65/2 upper-triangle pairs
#define GBLK  (NPAIR / 4) // 520 gram blocks, 4 waves each

#define IS2 0.70710678118654752440f

// ws layout: psi (64*1024 float2 = 512 KB) | partials (2*GBLK floats)
#define PART_OFF ((size_t)NPTS * DIM * sizeof(float2))

// ---------------------------------------------------------------------------
// Kernel 1: psi_i = U(x_i)|0>. 1024 threads (16 waves) per block, 64 blocks.
// One amplitude per thread: idx = tid; bits 0..5 cross-lane (shfl_xor),
// bits 6..9 cross-wave (LDS exchange).
//
// R4 lesson: keep loops ROLLED (unrolled version was I-fetch bound:
// FETCH_SIZE ~= 8 XCDs x code size, VALUBusy <1%).
// R6 lesson: no single-address device atomics (1024-deep ticket RMW chain
// serialized at ~100cyc each = 40us).
// 16 waves/CU (vs 4 in R5) hides the shuffle/LDS/barrier latency that
// bounded the 256-thread version.
//
// Verified algebra (absmax==0 in R4-R6):
//  - fused 1q gate M = RY(t)*RZ(x)*H; x angle is x[9-q] every layer.
//    cx=cos(x/2), sx=sin(x/2), c=cos(t/2), s=sin(t/2), p=(c+s)/sqrt2,
//    q=(c-s)/sqrt2:  m00=(q*cx,-p*sx) m01=(p*cx,-q*sx)
//                    m10=(p*cx, q*sx) m11=(-q*cx,-p*sx)   (store m00,m01)
//  - layer 0 acts on |0> -> product state (no exchanges)
//  - layer 5 ring diag + RY are data-independent outer unitaries -> cancel
//    in |<psi_j|psi_i>|^2 (c=1,s=0; ring skipped)
// ---------------------------------------------------------------------------
__global__ __launch_bounds__(1024) void state_kernel(
    const float* __restrict__ data,     // (64,10)
    const float* __restrict__ params,   // (5,2,10)
    float2* __restrict__ psi)           // (64,1024)
{
    const int i    = blockIdx.x;
    const int tid  = threadIdx.x;
    const int lane = tid & 63;

    __shared__ float4 mc[NLAYERS][NQ];   // (m00r, m00i, m01r, m01i)
    __shared__ float2 xbuf[DIM];         // cross-wave exchange (8 KB)

    // ---- precompute fused gate coefficients (50 threads, once) ----
    if (tid < NLAYERS * NQ) {
        const int L = tid / NQ, q = tid - L * NQ;
        const float xh = 0.5f * data[i * DFEAT + (9 - q)];
        const float cx = __cosf(xh), sx = __sinf(xh);
        float c = 1.f, s = 0.f;
        if (L != NLAYERS - 1) {
            const float th = 0.5f * params[L * 2 * NQ + q];
            c = __cosf(th); s = __sinf(th);
        }
        const float p = (c + s) * IS2, qm = (c - s) * IS2;
        mc[L][q] = make_float4(qm * cx, -p * sx, p * cx, -qm * sx);
    }
    __syncthreads();

    // ---- layer 0: product state ----
    float re, im;
    {
        float Pr = 1.f, Pi = 0.f;
#pragma unroll 1
        for (int q = 0; q < NQ; ++q) {
            const float4 m = mc[0][q];
            const int b = (tid >> q) & 1;
            const float fr = b ? m.z : m.x;      // u1 = m10, u0 = m00
            const float fi = b ? -m.w : m.y;
            const float nr = Pr * fr - Pi * fi;
            const float ni = Pr * fi + Pi * fr;
            Pr = nr; Pi = ni;
        }
        re = Pr; im = Pi;
    }

#pragma unroll 1
    for (int L = 0; L < NLAYERS; ++L) {
        if (L > 0) {
            // ---- qubits 0..5: cross-lane butterfly (rolled) ----
#pragma unroll 1
            for (int q = 0; q < 6; ++q) {
                const float4 m = mc[L][q];
                const int   b = (lane >> q) & 1;
                const float msr = b ? -m.x : m.x;   // m11r / m00r
                const float msi = m.y;              // m11i == m00i
                const float mpr = m.z;              // m10r == m01r
                const float mpi = b ? -m.w : m.w;   // m10i / m01i
                const float pr = __shfl_xor(re, 1 << q, 64);
                const float pi = __shfl_xor(im, 1 << q, 64);
                const float nr = msr * re - msi * im + mpr * pr - mpi * pi;
                const float ni = msr * im + msi * re + mpr * pi + mpi * pr;
                re = nr; im = ni;
            }
            // ---- qubits 6..9: cross-wave via LDS (rolled) ----
#pragma unroll 1
            for (int q = 6; q < NQ; ++q) {
                const float4 m = mc[L][q];
                const int   b = (tid >> q) & 1;
                const float msr = b ? -m.x : m.x;
                const float msi = m.y;
                const float mpr = m.z;
                const float mpi = b ? -m.w : m.w;
                xbuf[tid] = make_float2(re, im);
                __syncthreads();
                const float2 p2 = xbuf[tid ^ (1 << q)];
                const float nr = msr * re - msi * im + mpr * p2.x - mpi * p2.y;
                const float ni = msr * im + msi * re + mpr * p2.y + mpi * p2.x;
                re = nr; im = ni;
                __syncthreads();
            }
        }

        // ---- crz ring diagonal (skip layer 5: cancels) ----
        if (L < NLAYERS - 1) {
            const float* rg = params + L * 2 * NQ + NQ;
            float ph = 0.f;
#pragma unroll 1
            for (int n = 0; n < NQ; ++n) {
                const int   nn = (n == 9) ? 0 : (n + 1);
                const float g  = rg[n];     // wave-uniform -> s_load
                const float t  = (((tid >> nn) & 1) ? 0.5f : -0.5f) * g;
                ph += ((tid >> n) & 1) ? t : 0.f;
            }
            const float s = __sinf(ph), c = __cosf(ph);
            const float nr = re * c - im * s;
            const float ni = re * s + im * c;
            re = nr; im = ni;
        }
    }

    psi[i * DIM + tid] = make_float2(re, im);
}

// ---------------------------------------------------------------------------
// Kernel 2: gram partials over the UPPER TRIANGLE only.
// Wave w (global) -> pair (i,j), j>=i, via closed-form triangle indexing.
// Each wave computes k = |<psi_j|psi_i>|^2, weights off-diagonals by 2, and
// the block's 4 waves combine in LDS; thread 0 writes 2 partial floats.
// Every partials[] entry is written unconditionally -> no init needed under
// the harness 0xAA re-poison. No atomics (R6 lesson).
// ---------------------------------------------------------------------------
__global__ __launch_bounds__(256) void gram_kernel(
    const float4* __restrict__ psi4,    // (64, 512) float4 view of psi
    const float* __restrict__ labels,   // (64,)
    float* __restrict__ partials)       // (2*GBLK,)
{
    __shared__ float sm[2][4];
    const int wave = threadIdx.x >> 6;
    const int lane = threadIdx.x & 63;
    const int w    = blockIdx.x * 4 + wave;   // 0..2079

    // triangle index: i = row with C(i) = 64i - i(i-1)/2 <= w < C(i+1)
    int i = (int)((129.0f - sqrtf(16641.0f - 8.0f * (float)w)) * 0.5f);
    int Ci = 64 * i - ((i * (i - 1)) >> 1);
    while (w < Ci)            { --i; Ci = 64 * i - ((i * (i - 1)) >> 1); }
    while (w >= Ci + 64 - i)  { Ci += 64 - i; ++i; }
    const int j = i + (w - Ci);

    const float4* a = psi4 + i * (DIM / 2);
    const float4* b = psi4 + j * (DIM / 2);

    float zr = 0.f, zi = 0.f;   // <psi_j|psi_i> = sum conj(b)*a
#pragma unroll
    for (int r = 0; r < 8; ++r) {
        const int k = (r << 6) | lane;
        const float4 av = a[k], bv = b[k];
        zr += bv.x * av.x + bv.y * av.y + bv.z * av.z + bv.w * av.w;
        zi += bv.x * av.y - bv.y * av.x + bv.z * av.w - bv.w * av.z;
    }
#pragma unroll
    for (int off = 32; off; off >>= 1) {
        zr += __shfl_xor(zr, off, 64);
        zi += __shfl_xor(zi, off, 64);
    }

    if (lane == 0) {
        const float k = zr * zr + zi * zi;
        const float wgt = (i == j) ? 1.f : 2.f;
        sm[0][wave] = wgt * labels[i] * labels[j] * k;
        sm[1][wave] = wgt * k * k;
    }
    __syncthreads();
    if (threadIdx.x == 0) {
        partials[2 * blockIdx.x]     = sm[0][0] + sm[0][1] + sm[0][2] + sm[0][3];
        partials[2 * blockIdx.x + 1] = sm[1][0] + sm[1][1] + sm[1][2] + sm[1][3];
    }
}

// ---------------------------------------------------------------------------
// Kernel 3: final KTA. Reads 2*GBLK partials + labels. One 256-thread block.
// out = slk / sqrt(skk * (sum l^2)^2)
// ---------------------------------------------------------------------------
__global__ __launch_bounds__(256) void reduce_kernel(
    const float* __restrict__ partials,
    const float* __restrict__ labels,
    float* __restrict__ out)
{
    __shared__ float sm[3][4];
    const int tid  = threadIdx.x;
    const int lane = tid & 63;
    const int wave = tid >> 6;

    float slk = 0.f, skk = 0.f, sl2 = 0.f;
    for (int p = tid; p < GBLK; p += 256) {
        slk += partials[2 * p];
        skk += partials[2 * p + 1];
    }
    if (tid < NPTS) { const float l = labels[tid]; sl2 = l * l; }

#pragma unroll
    for (int off = 32; off; off >>= 1) {
        slk += __shfl_xor(slk, off, 64);
        skk += __shfl_xor(skk, off, 64);
        sl2 += __shfl_xor(sl2, off, 64);
    }
    if (lane == 0) { sm[0][wave] = slk; sm[1][wave] = skk; sm[2][wave] = sl2; }
    __syncthreads();
    if (tid == 0) {
        const float a = sm[0][0] + sm[0][1] + sm[0][2] + sm[0][3];
        const float b = sm[1][0] + sm[1][1] + sm[1][2] + sm[1][3];
        const float c = sm[2][0] + sm[2][1] + sm[2][2] + sm[2][3];
        out[0] = a / sqrtf(b * (c * c));
    }
}

extern "C" void kernel_launch(void* const* d_in, const int* in_sizes, int n_in,
                              void* d_out, int out_size, void* d_ws, size_t ws_size,
                              hipStream_t stream) {
    const float* data   = (const float*)d_in[0];  // (64,10)
    const float* labels = (const float*)d_in[1];  // (64,)
    const float* params = (const float*)d_in[2];  // (5,2,10)
    float* out = (float*)d_out;

    float2* psi      = (float2*)d_ws;
    float*  partials = (float*)((char*)d_ws + PART_OFF);

    state_kernel <<<NPTS, 1024, 0, stream>>>(data, params, psi);
    gram_kernel  <<<GBLK,  256, 0, stream>>>((const float4*)psi, labels, partials);
    reduce_kernel<<<1,     256, 0, stream>>>(partials, labels, out);
}